// Round 10
// baseline (99.463 us; speedup 1.0000x reference)
//
#include <hip/hip_runtime.h>
#include <stdint.h>

// DynamicMaxPool: per-column k-max pooling with order preservation.
// x: [B=16, T=4096, C=256] f32. For each (b,c): keep the k largest of the
// first pr rows (ties -> lower row index, stable), compacted to rows 0..k-1
// in original row order; rows k..T-1 zero. k is per-batch.
//
//  K0: x[b][t][c] -> sortable keys xT[b][c][t]  (coalesced transpose)
//  K1: 2 waves/column, 32 vals/lane in regs; WAVE-PRIVATE double-buffered
//      histograms -> 1 barrier/pass (5 total). Round-9 bug: end-of-pass zero
//      ran only for pass<2, so pass 3 counted onto pass-1's stale buffer ->
//      under-kept ties -> stale keys in slab (absmax 3295 = ~0xBAB204D8).
//      Fixed: zero buf^1 for pass<3 (ordered after all pass-(p-1) scans by
//      the pass-p barrier; owner-only planes).
//  K2: slab [b][c][pos] -> out[b][pos][c] transpose + zero-fill.

constexpr int T_ROWS = 4096;
constexpr int C_COLS = 256;
constexpr int NBATCH = 16;
constexpr int SELBLK = 512;               // 8 waves = 4 cols x 2 halves
constexpr int NWAVES = SELBLK / 64;
constexpr int SUBW   = 2;                 // sub-planes per wave
constexpr size_t NTOT = (size_t)NBATCH * T_ROWS * C_COLS;

__device__ __forceinline__ int compute_k(const int* lengths, const int* pool_ranges,
                                         const int* p_top_k, const int* p_layer,
                                         const int* p_total, int b, int* pr_out)
{
    int pr = pool_ranges[b];
    pr = pr < 0 ? 0 : (pr > T_ROWS ? T_ROWS : pr);
    const int len   = lengths[b];
    const int top_k = p_top_k[0];
    const int tot   = p_total[0];
    const int num   = tot - p_layer[0];
    int k = (num * len + tot - 1) / tot;   // ceil, positive ints
    if (k < top_k) k = top_k;
    if (k > pr)    k = pr;
    *pr_out = pr;
    return k;
}

// ---- K0: transpose + key transform. grid 4096 (b, 64 t-tiles, 4 c-tiles) ----
__global__ __launch_bounds__(256)
void transpose_key_kernel(const float* __restrict__ x, uint32_t* __restrict__ xT)
{
    __shared__ uint32_t tile[64][65];
    const int bid = blockIdx.x;
    const int b   = bid >> 8;
    const int tt  = (bid >> 2) & 63;
    const int ct  = bid & 3;
    const int t0  = tt * 64, c0 = ct * 64;
    const int tid = threadIdx.x;
    const int qq  = tid & 15;
    const int rr  = tid >> 4;

    #pragma unroll
    for (int it = 0; it < 4; ++it) {
        const int r = it * 16 + rr;
        const float4 v = *reinterpret_cast<const float4*>(
            x + ((size_t)(b * T_ROWS + t0 + r) << 8) + c0 + qq * 4);
        const uint32_t w4[4] = {__float_as_uint(v.x), __float_as_uint(v.y),
                                __float_as_uint(v.z), __float_as_uint(v.w)};
        #pragma unroll
        for (int j = 0; j < 4; ++j)
            tile[qq * 4 + j][r] = w4[j] ^ ((w4[j] >> 31) ? 0xFFFFFFFFu : 0x80000000u);
    }
    __syncthreads();
    #pragma unroll
    for (int it = 0; it < 4; ++it) {
        const int cl = it * 16 + rr;
        uint4 o;
        o.x = tile[cl][qq * 4 + 0];
        o.y = tile[cl][qq * 4 + 1];
        o.z = tile[cl][qq * 4 + 2];
        o.w = tile[cl][qq * 4 + 3];
        *reinterpret_cast<uint4*>(
            xT + ((size_t)(b * C_COLS + c0 + cl) << 12) + t0 + qq * 4) = o;
    }
}

// ---- K1: select. grid 1024 blocks x 512 thr (8 waves: 4 cols x 2 halves) ----
__global__ __launch_bounds__(SELBLK, 6)
void kmax_select_kernel(const uint32_t* __restrict__ xT,
                        const int* __restrict__ lengths,
                        const int* __restrict__ pool_ranges,
                        const int* __restrict__ p_top_k,
                        const int* __restrict__ p_layer,
                        const int* __restrict__ p_total,
                        float* __restrict__ out,
                        float* __restrict__ ws)
{
    // Wave-private planes: hist[buf][wid][sub][256]. Owner-only writes.
    __shared__ uint32_t hist[2][NWAVES][SUBW][256];   // 32 KB
    __shared__ uint32_t wtot[4];

    const int t    = threadIdx.x;
    const int lane = t & 63;
    const int wid  = t >> 6;
    const int col  = wid >> 1;            // local column 0..3
    const int half = wid & 1;             // rows [half*2048, +2048)
    const int bid  = blockIdx.x;
    const int b    = bid >> 6;
    const int cg   = bid & 63;
    const int c    = cg * 4 + col;

    int pr;
    const int k = compute_k(lengths, pool_ranges, p_top_k, p_layer, p_total, b, &pr);

    // contiguous half-column loads: 8 b128, depth-4 pipeline fused with mask.
    const uint4* cp = reinterpret_cast<const uint4*>(
                          xT + ((size_t)(b * C_COLS + c) << 12)) + half * 512 + lane;
    const int rb = half * 2048 + lane * 4;
    uint32_t u[32];                        // u[i*4+j] = row rb + i*256 + j
    uint4 pf[4];
    #pragma unroll
    for (int i = 0; i < 4; ++i) pf[i] = cp[i * 64];
    #pragma unroll
    for (int i = 0; i < 8; ++i) {
        const uint4 v = pf[i & 3];
        if (i + 4 < 8) pf[i & 3] = cp[(i + 4) * 64];
        const int rowb = rb + i * 256;
        u[i * 4 + 0] = (rowb + 0 < pr) ? v.x : 0u;
        u[i * 4 + 1] = (rowb + 1 < pr) ? v.y : 0u;
        u[i * 4 + 2] = (rowb + 2 < pr) ? v.z : 0u;
        u[i * 4 + 3] = (rowb + 3 < pr) ? v.w : 0u;
        asm("" : "+v"(u[i*4+0]), "+v"(u[i*4+1]), "+v"(u[i*4+2]), "+v"(u[i*4+3]));
    }

    uint32_t prefix = 0u, pmask = 0u, rem = (uint32_t)k;
    if (k > 0) {
        // zero BOTH buffers' own planes (owner-only; program order suffices
        // before pass-0 counting; partner's zero ordered by pass-0 barrier).
        {
            uint4* z0 = reinterpret_cast<uint4*>(&hist[0][wid][0][0]);
            uint4* z1 = reinterpret_cast<uint4*>(&hist[1][wid][0][0]);
            const uint4 z4 = make_uint4(0u, 0u, 0u, 0u);
            #pragma unroll
            for (int z = 0; z < 2; ++z) { z0[z * 64 + lane] = z4; z1[z * 64 + lane] = z4; }
        }

        #pragma unroll 1
        for (int pass = 0; pass < 4; ++pass) {
            const int shift = 24 - 8 * pass;
            const int buf   = pass & 1;
            // count into my planes at slot (d + rot)&255, d = 255-bin,
            // rot = 4*(2*wid+sub): hot bins spread across subs and banks.
            #pragma unroll
            for (int m = 0; m < 32; ++m) {
                const uint32_t ui = u[m];
                if ((ui & pmask) == prefix) {
                    const uint32_t d   = 255u - ((ui >> shift) & 255u);
                    const uint32_t sub = shift ? ((ui >> (shift - 1)) & 1u)
                                               : ((uint32_t)lane & 1u);
                    atomicAdd(&hist[buf][wid][sub]
                                   [(d + 4u * (2u * (uint32_t)wid + sub)) & 255u], 1u);
                }
            }
            __syncthreads();
            // scan: lane owns descending positions d = 4*lane..4*lane+3;
            // contiguous-16B per (plane,sub) -> conflict-free.
            uint32_t c4[4] = {0u, 0u, 0u, 0u};
            #pragma unroll
            for (int w2 = 0; w2 < 2; ++w2) {
                const int pw = col * 2 + w2;
                #pragma unroll
                for (int s = 0; s < SUBW; ++s) {
                    const uint4 a = *reinterpret_cast<const uint4*>(
                        &hist[buf][pw][s][(4u * (uint32_t)lane +
                                           4u * (2u * (uint32_t)pw + (uint32_t)s)) & 255u]);
                    c4[0] += a.x; c4[1] += a.y; c4[2] += a.z; c4[3] += a.w;
                }
            }
            uint32_t loc[4], ssum = 0;
            #pragma unroll
            for (int q = 0; q < 4; ++q) { loc[q] = ssum; ssum += c4[q]; }
            uint32_t incl = ssum;
            #pragma unroll
            for (int off = 1; off < 64; off <<= 1) {
                const uint32_t nb = __shfl_up(incl, (unsigned)off, 64);
                if (lane >= off) incl += nb;
            }
            const uint32_t gexcl = incl - ssum;
            uint32_t sel = 0, nrem = 0;
            bool found = false;
            #pragma unroll
            for (int q = 0; q < 4; ++q) {
                const uint32_t sbb = gexcl + loc[q];    // elems in higher bins
                if (sbb < rem && sbb + c4[q] >= rem) {  // unique crossing
                    sel   = 255u - (uint32_t)(4 * lane + q);
                    nrem  = rem - sbb;
                    found = true;
                }
            }
            const unsigned long long fm = __ballot(found);
            const int src = __ffsll(fm) - 1;
            sel  = __shfl(sel,  src, 64);
            nrem = __shfl(nrem, src, 64);
            prefix |= sel << shift;
            pmask  |= 0xFFu << shift;
            rem = nrem;
            // Zero my planes of the OTHER buffer (used by pass+1): safe —
            // the pass-p barrier orders it after all pass-(p-1) scans of that
            // buffer. MUST run for pass 0,1,2 (round-9 bug: pass<2 left
            // pass-1 counts in buf1 for pass 3).
            if (pass < 3) {
                uint4* zb = reinterpret_cast<uint4*>(&hist[buf ^ 1][wid][0][0]);
                const uint4 z4 = make_uint4(0u, 0u, 0u, 0u);
                #pragma unroll
                for (int z = 0; z < 2; ++z) zb[z * 64 + lane] = z4;
            }
        }

        // ---- keep + compact; cross-wave base via wtot, then in-place write --
        const uint32_t th = prefix, tn = rem;
        if (half == 0) {                   // wave 0 of the column publishes totals
            uint32_t pk = 0;
            #pragma unroll
            for (int m = 0; m < 32; ++m) {
                const int rowb = rb + (m >> 2) * 256 + (m & 3);
                const uint32_t ui = u[m];
                pk += ((ui > th) ? 0x10000u : 0u)
                    + (((rowb < pr) && ui == th) ? 1u : 0u);
            }
            #pragma unroll
            for (int off = 32; off >= 1; off >>= 1) pk += __shfl_xor(pk, off, 64);
            if (lane == 0) wtot[col] = pk;
        }
        __syncthreads();
        const uint32_t base0 = half ? wtot[col] : 0u;

        uint32_t G = base0 >> 16, E = base0 & 0xFFFFu;
        float* dst = ws + ((size_t)(b * C_COLS + c) << 12);
        #pragma unroll
        for (int i = 0; i < 8; ++i) {
            const int rowb = rb + i * 256;
            uint32_t gt[4], eq[4], pk = 0;
            #pragma unroll
            for (int j = 0; j < 4; ++j) {
                const uint32_t ui = u[i * 4 + j];
                gt[j] = (ui > th) ? 1u : 0u;
                eq[j] = ((rowb + j < pr) && ui == th) ? 1u : 0u;
                pk += (gt[j] << 16) | eq[j];
            }
            uint32_t incl = pk;
            #pragma unroll
            for (int off = 1; off < 64; off <<= 1) {
                const uint32_t nb = __shfl_up(incl, (unsigned)off, 64);
                if (lane >= off) incl += nb;
            }
            const uint32_t tot  = __shfl(incl, 63, 64);
            const uint32_t base = incl - pk;
            uint32_t g = G + (base >> 16), e = E + (base & 0xFFFFu);
            #pragma unroll
            for (int j = 0; j < 4; ++j) {
                if (gt[j] || (eq[j] && e < tn)) {
                    const uint32_t pos  = g + (e < tn ? e : tn);
                    const uint32_t ui   = u[i * 4 + j];
                    const uint32_t bits = ui ^ ((ui >> 31) ? 0x80000000u : 0xFFFFFFFFu);
                    dst[pos] = __uint_as_float(bits);
                }
                g += gt[j];
                e += eq[j];
            }
            G += tot >> 16;
            E += tot & 0xFFFFu;
        }
    }

    // Output 1: pool_result_ranges (k per batch), as float32
    if (cg == 0 && t == 0)
        out[NTOT + (size_t)b] = (float)k;
}

// ---- K2: slab [b][c][pos] -> out[b][pos][c] + zero-fill. grid 4096. ----
__global__ __launch_bounds__(256)
void finalize_kernel(const float* __restrict__ ws,
                     const int* __restrict__ lengths,
                     const int* __restrict__ pool_ranges,
                     const int* __restrict__ p_top_k,
                     const int* __restrict__ p_layer,
                     const int* __restrict__ p_total,
                     float* __restrict__ out)
{
    __shared__ float tile[64][65];
    const int bid  = blockIdx.x;
    const int b    = bid >> 8;
    const int pt   = (bid >> 2) & 63;
    const int ct   = bid & 3;
    const int pos0 = pt * 64, c0 = ct * 64;

    int pr;
    const int k = compute_k(lengths, pool_ranges, p_top_k, p_layer, p_total, b, &pr);

    const int tid = threadIdx.x;
    const int qq  = tid & 15;
    const int rr  = tid >> 4;
    float4* out4 = reinterpret_cast<float4*>(out);
    const float4 z4 = make_float4(0.f, 0.f, 0.f, 0.f);

    if (pos0 < k) {
        const float4* ws4 = reinterpret_cast<const float4*>(ws);
        #pragma unroll
        for (int it = 0; it < 4; ++it) {
            const int cl = it * 16 + rr;
            const float4 v = ws4[((size_t)(b * C_COLS + c0 + cl) << 10)
                                 + (pos0 >> 2) + qq];
            tile[cl][qq * 4 + 0] = v.x;
            tile[cl][qq * 4 + 1] = v.y;
            tile[cl][qq * 4 + 2] = v.z;
            tile[cl][qq * 4 + 3] = v.w;
        }
        __syncthreads();
        #pragma unroll
        for (int it = 0; it < 4; ++it) {
            const int r = it * 16 + rr;
            float4 v;
            v.x = tile[qq * 4 + 0][r];
            v.y = tile[qq * 4 + 1][r];
            v.z = tile[qq * 4 + 2][r];
            v.w = tile[qq * 4 + 3][r];
            if (pos0 + r >= k) v = z4;        // straddling tile: zero past k
            out4[((size_t)(b * T_ROWS + pos0 + r) << 6) + (c0 >> 2) + qq] = v;
        }
    } else {
        #pragma unroll
        for (int it = 0; it < 4; ++it) {
            const int r = it * 16 + rr;
            out4[((size_t)(b * T_ROWS + pos0 + r) << 6) + (c0 >> 2) + qq] = z4;
        }
    }
}

extern "C" void kernel_launch(void* const* d_in, const int* in_sizes, int n_in,
                              void* d_out, int out_size, void* d_ws, size_t ws_size,
                              hipStream_t stream)
{
    const float* x            = (const float*)d_in[0];
    const int*   lengths      = (const int*)d_in[1];
    const int*   pool_ranges  = (const int*)d_in[2];
    const int*   top_k        = (const int*)d_in[3];
    const int*   layer        = (const int*)d_in[4];
    const int*   total_layers = (const int*)d_in[5];
    float*       out          = (float*)d_out;
    float*       ws           = (float*)d_ws;   // 64 MiB: xT keys, then slab (in-place)

    hipLaunchKernelGGL(transpose_key_kernel, dim3(4096), dim3(256), 0, stream,
                       x, (uint32_t*)ws);
    hipLaunchKernelGGL(kmax_select_kernel, dim3(1024), dim3(SELBLK), 0, stream,
                       (const uint32_t*)ws, lengths, pool_ranges,
                       top_k, layer, total_layers, out, ws);
    hipLaunchKernelGGL(finalize_kernel, dim3(4096), dim3(256), 0, stream,
                       ws, lengths, pool_ranges, top_k, layer, total_layers, out);
}

// Round 11
// 95.184 us; speedup vs baseline: 1.0450x; 1.0450x over previous
//
#include <hip/hip_runtime.h>
#include <stdint.h>

// DynamicMaxPool: per-column k-max pooling with order preservation.
// x: [B=16, T=4096, C=256] f32. For each (b,c): keep the k largest of the
// first pr rows (ties -> lower row index, stable), compacted to rows 0..k-1
// in original row order; rows k..T-1 zero. k is per-batch.
//
//  K0: x[b][t][c] -> sortable keys xT[b][c][t]  (coalesced transpose)
//  K1: 1 wave/column, ZERO barriers. Rounds 5-10 lesson: the compiler never
//      keeps the column register-resident (VGPR=40 w/ 55+ live => scratch),
//      so this version RE-READS the column from L2 each phase (5 sweeps of a
//      64KB/block working set; L2-resident). Persistent state ~8 regs -> no
//      spill by construction. Hist: single-buffer, zero-after-read in the
//      scan; NSUB=8 data-dependent sub + 4*sub bank rotation; invalid rows
//      gated out of counting (not masked-to-0: r10 funneled up to 2048
//      same-word atomics into the bin-255 word).
//  K2: slab [b][c][pos] -> out[b][pos][c] transpose + zero-fill.

constexpr int T_ROWS = 4096;
constexpr int C_COLS = 256;
constexpr int NBATCH = 16;
constexpr int NSUB   = 8;
constexpr size_t NTOT = (size_t)NBATCH * T_ROWS * C_COLS;

__device__ __forceinline__ int compute_k(const int* lengths, const int* pool_ranges,
                                         const int* p_top_k, const int* p_layer,
                                         const int* p_total, int b, int* pr_out)
{
    int pr = pool_ranges[b];
    pr = pr < 0 ? 0 : (pr > T_ROWS ? T_ROWS : pr);
    const int len   = lengths[b];
    const int top_k = p_top_k[0];
    const int tot   = p_total[0];
    const int num   = tot - p_layer[0];
    int k = (num * len + tot - 1) / tot;   // ceil, positive ints
    if (k < top_k) k = top_k;
    if (k > pr)    k = pr;
    *pr_out = pr;
    return k;
}

// ---- K0: transpose + key transform. grid 4096 (b, 64 t-tiles, 4 c-tiles) ----
__global__ __launch_bounds__(256)
void transpose_key_kernel(const float* __restrict__ x, uint32_t* __restrict__ xT)
{
    __shared__ uint32_t tile[64][65];
    const int bid = blockIdx.x;
    const int b   = bid >> 8;
    const int tt  = (bid >> 2) & 63;
    const int ct  = bid & 3;
    const int t0  = tt * 64, c0 = ct * 64;
    const int tid = threadIdx.x;
    const int qq  = tid & 15;
    const int rr  = tid >> 4;

    #pragma unroll
    for (int it = 0; it < 4; ++it) {
        const int r = it * 16 + rr;
        const float4 v = *reinterpret_cast<const float4*>(
            x + ((size_t)(b * T_ROWS + t0 + r) << 8) + c0 + qq * 4);
        const uint32_t w4[4] = {__float_as_uint(v.x), __float_as_uint(v.y),
                                __float_as_uint(v.z), __float_as_uint(v.w)};
        #pragma unroll
        for (int j = 0; j < 4; ++j)
            tile[qq * 4 + j][r] = w4[j] ^ ((w4[j] >> 31) ? 0xFFFFFFFFu : 0x80000000u);
    }
    __syncthreads();
    #pragma unroll
    for (int it = 0; it < 4; ++it) {
        const int cl = it * 16 + rr;
        uint4 o;
        o.x = tile[cl][qq * 4 + 0];
        o.y = tile[cl][qq * 4 + 1];
        o.z = tile[cl][qq * 4 + 2];
        o.w = tile[cl][qq * 4 + 3];
        *reinterpret_cast<uint4*>(
            xT + ((size_t)(b * C_COLS + c0 + cl) << 12) + t0 + qq * 4) = o;
    }
}

// ---- K1: select. grid 1024 blocks x 256 thr (4 waves = 4 columns). ----
__global__ __launch_bounds__(256, 4)
void kmax_select_kernel(const uint32_t* __restrict__ xT,
                        const int* __restrict__ lengths,
                        const int* __restrict__ pool_ranges,
                        const int* __restrict__ p_top_k,
                        const int* __restrict__ p_layer,
                        const int* __restrict__ p_total,
                        float* __restrict__ out,
                        float* __restrict__ ws)
{
    __shared__ uint32_t hist[4][NSUB][256];    // 32 KB, wave-private slices

    const int t    = threadIdx.x;
    const int lane = t & 63;
    const int wid  = t >> 6;
    const int bid  = blockIdx.x;
    const int b    = bid >> 6;
    const int cg   = bid & 63;
    const int c    = cg * 4 + wid;

    int pr;
    const int k = compute_k(lengths, pool_ranges, p_top_k, p_layer, p_total, b, &pr);

    const size_t colbase = (size_t)(b * C_COLS + c) << 12;
    const uint4* cp = reinterpret_cast<const uint4*>(xT + colbase) + lane;
    const int rb = lane * 4;                   // lane's row base within a sweep step

    if (k > 0) {
        uint32_t* hp = &hist[wid][0][0];
        // initial zero of my wave's hist (wave-order: precedes my atomics)
        {
            uint4* hz = reinterpret_cast<uint4*>(hp);
            const uint4 z4 = make_uint4(0u, 0u, 0u, 0u);
            #pragma unroll
            for (int z = 0; z < 8; ++z) hz[z * 64 + lane] = z4;
        }

        uint32_t prefix = 0u, pmask = 0u, rem = (uint32_t)k;

        #pragma unroll 1
        for (int pass = 0; pass < 4; ++pass) {
            const int shift     = 24 - 8 * pass;
            const int sub_shift = shift ? (shift - 3) : 0;
            // ---- count sweep: re-read column (L2-resident), gated atomics.
            //      Invalid rows (>= pr) are gated OUT (never counted).
            {
                uint4 pf[4];
                #pragma unroll
                for (int i = 0; i < 4; ++i) pf[i] = cp[i * 64];
                #pragma unroll
                for (int i = 0; i < 16; ++i) {
                    const uint4 v = pf[i & 3];
                    if (i + 4 < 16) pf[i & 3] = cp[(i + 4) * 64];
                    const int rowb = i * 256 + rb;
                    const uint32_t raw[4] = {v.x, v.y, v.z, v.w};
                    #pragma unroll
                    for (int j = 0; j < 4; ++j) {
                        const uint32_t ui = raw[j];
                        if ((rowb + j < pr) && ((ui & pmask) == prefix)) {
                            const uint32_t d   = 255u - ((ui >> shift) & 255u);
                            const uint32_t sub = (ui >> sub_shift) & 7u;
                            // 8 sub-copies of a bin on 8 distinct banks
                            atomicAdd(&hp[sub * 256u + ((d + 4u * sub) & 255u)], 1u);
                        }
                    }
                }
            }
            // ---- scan (descending): lane owns positions 4*lane..4*lane+3.
            //      Zero-after-read leaves the hist clean for the next pass.
            uint32_t c4[4] = {0u, 0u, 0u, 0u};
            {
                const uint4 z4 = make_uint4(0u, 0u, 0u, 0u);
                #pragma unroll
                for (int s = 0; s < NSUB; ++s) {
                    uint32_t* ap = &hp[s * 256u + ((4u * (uint32_t)lane + 4u * s) & 255u)];
                    const uint4 a = *reinterpret_cast<const uint4*>(ap);
                    *reinterpret_cast<uint4*>(ap) = z4;
                    c4[0] += a.x; c4[1] += a.y; c4[2] += a.z; c4[3] += a.w;
                }
            }
            uint32_t loc[4], ssum = 0;
            #pragma unroll
            for (int q = 0; q < 4; ++q) { loc[q] = ssum; ssum += c4[q]; }
            uint32_t incl = ssum;
            #pragma unroll
            for (int off = 1; off < 64; off <<= 1) {
                const uint32_t nb = __shfl_up(incl, (unsigned)off, 64);
                if (lane >= off) incl += nb;
            }
            const uint32_t gexcl = incl - ssum;
            uint32_t sel = 0, nrem = 0;
            bool found = false;
            #pragma unroll
            for (int q = 0; q < 4; ++q) {
                const uint32_t sbb = gexcl + loc[q];    // elems in higher bins
                if (sbb < rem && sbb + c4[q] >= rem) {  // unique crossing
                    sel   = 255u - (uint32_t)(4 * lane + q);
                    nrem  = rem - sbb;
                    found = true;
                }
            }
            const unsigned long long fm = __ballot(found);
            const int src = __ffsll(fm) - 1;
            sel  = __shfl(sel,  src, 64);
            nrem = __shfl(nrem, src, 64);
            prefix |= sel << shift;
            pmask  |= 0xFFu << shift;
            rem = nrem;
        }

        // ---- keep + compact sweep: reload; write dense slab IN-PLACE.
        //      Safe: stores at iter i target pos <= i*256+255, prefetched
        //      loads target rows >= (i+1)*256 — always disjoint.
        const uint32_t th = prefix, tn = rem;
        uint32_t G = 0, E = 0;
        float* dst = ws + colbase;
        uint4 pf[4];
        #pragma unroll
        for (int i = 0; i < 4; ++i) pf[i] = cp[i * 64];
        #pragma unroll
        for (int i = 0; i < 16; ++i) {
            const uint4 v = pf[i & 3];
            if (i + 4 < 16) pf[i & 3] = cp[(i + 4) * 64];
            const int rowb = i * 256 + rb;
            const uint32_t raw[4] = {v.x, v.y, v.z, v.w};
            uint32_t gt[4], eq[4], pk = 0, uu[4];
            #pragma unroll
            for (int j = 0; j < 4; ++j) {
                uu[j] = (rowb + j < pr) ? raw[j] : 0u;
                gt[j] = (uu[j] > th) ? 1u : 0u;
                eq[j] = ((rowb + j < pr) && uu[j] == th) ? 1u : 0u;
                pk += (gt[j] << 16) | eq[j];
            }
            uint32_t incl = pk;
            #pragma unroll
            for (int off = 1; off < 64; off <<= 1) {
                const uint32_t nb = __shfl_up(incl, (unsigned)off, 64);
                if (lane >= off) incl += nb;
            }
            const uint32_t tot  = __shfl(incl, 63, 64);
            const uint32_t base = incl - pk;
            uint32_t g = G + (base >> 16), e = E + (base & 0xFFFFu);
            #pragma unroll
            for (int j = 0; j < 4; ++j) {
                if (gt[j] || (eq[j] && e < tn)) {
                    const uint32_t pos  = g + (e < tn ? e : tn);
                    const uint32_t bits = uu[j] ^ ((uu[j] >> 31) ? 0x80000000u
                                                                 : 0xFFFFFFFFu);
                    dst[pos] = __uint_as_float(bits);
                }
                g += gt[j];
                e += eq[j];
            }
            G += tot >> 16;
            E += tot & 0xFFFFu;
        }
    }

    // Output 1: pool_result_ranges (k per batch), as float32
    if (cg == 0 && t == 0)
        out[NTOT + (size_t)b] = (float)k;
}

// ---- K2: slab [b][c][pos] -> out[b][pos][c] + zero-fill. grid 4096. ----
__global__ __launch_bounds__(256)
void finalize_kernel(const float* __restrict__ ws,
                     const int* __restrict__ lengths,
                     const int* __restrict__ pool_ranges,
                     const int* __restrict__ p_top_k,
                     const int* __restrict__ p_layer,
                     const int* __restrict__ p_total,
                     float* __restrict__ out)
{
    __shared__ float tile[64][65];
    const int bid  = blockIdx.x;
    const int b    = bid >> 8;
    const int pt   = (bid >> 2) & 63;
    const int ct   = bid & 3;
    const int pos0 = pt * 64, c0 = ct * 64;

    int pr;
    const int k = compute_k(lengths, pool_ranges, p_top_k, p_layer, p_total, b, &pr);

    const int tid = threadIdx.x;
    const int qq  = tid & 15;
    const int rr  = tid >> 4;
    float4* out4 = reinterpret_cast<float4*>(out);
    const float4 z4 = make_float4(0.f, 0.f, 0.f, 0.f);

    if (pos0 < k) {
        const float4* ws4 = reinterpret_cast<const float4*>(ws);
        #pragma unroll
        for (int it = 0; it < 4; ++it) {
            const int cl = it * 16 + rr;
            const float4 v = ws4[((size_t)(b * C_COLS + c0 + cl) << 10)
                                 + (pos0 >> 2) + qq];
            tile[cl][qq * 4 + 0] = v.x;
            tile[cl][qq * 4 + 1] = v.y;
            tile[cl][qq * 4 + 2] = v.z;
            tile[cl][qq * 4 + 3] = v.w;
        }
        __syncthreads();
        #pragma unroll
        for (int it = 0; it < 4; ++it) {
            const int r = it * 16 + rr;
            float4 v;
            v.x = tile[qq * 4 + 0][r];
            v.y = tile[qq * 4 + 1][r];
            v.z = tile[qq * 4 + 2][r];
            v.w = tile[qq * 4 + 3][r];
            if (pos0 + r >= k) v = z4;        // straddling tile: zero past k
            out4[((size_t)(b * T_ROWS + pos0 + r) << 6) + (c0 >> 2) + qq] = v;
        }
    } else {
        #pragma unroll
        for (int it = 0; it < 4; ++it) {
            const int r = it * 16 + rr;
            out4[((size_t)(b * T_ROWS + pos0 + r) << 6) + (c0 >> 2) + qq] = z4;
        }
    }
}

extern "C" void kernel_launch(void* const* d_in, const int* in_sizes, int n_in,
                              void* d_out, int out_size, void* d_ws, size_t ws_size,
                              hipStream_t stream)
{
    const float* x            = (const float*)d_in[0];
    const int*   lengths      = (const int*)d_in[1];
    const int*   pool_ranges  = (const int*)d_in[2];
    const int*   top_k        = (const int*)d_in[3];
    const int*   layer        = (const int*)d_in[4];
    const int*   total_layers = (const int*)d_in[5];
    float*       out          = (float*)d_out;
    float*       ws           = (float*)d_ws;   // 64 MiB: xT keys, then slab (in-place)

    hipLaunchKernelGGL(transpose_key_kernel, dim3(4096), dim3(256), 0, stream,
                       x, (uint32_t*)ws);
    hipLaunchKernelGGL(kmax_select_kernel, dim3(1024), dim3(256), 0, stream,
                       (const uint32_t*)ws, lengths, pool_ranges,
                       top_k, layer, total_layers, out, ws);
    hipLaunchKernelGGL(finalize_kernel, dim3(4096), dim3(256), 0, stream,
                       ws, lengths, pool_ranges, top_k, layer, total_layers, out);
}